// Round 2
// baseline (119.620 us; speedup 1.0000x reference)
//
#include <hip/hip_runtime.h>
#include <math.h>

// RoPE: x (B=16, S=8192, D=128) fp32, interleaved even/odd pairs.
// Reference ignores token_positions; angle = s * theta^(-2i/D), i in [0,64).
// out[2i]   = x[2i]*cos - x[2i+1]*sin
// out[2i+1] = x[2i]*sin + x[2i+1]*cos
//
// Structure: thread t handles float4 indices {t, t+Q, t+2Q, t+3Q}, Q = TOTAL/4.
// Q >> 5 = 32768 is a multiple of S=8192  -> same s for all four
// Q & 31 = 0                              -> same j (same freq pair)
// => one exp2 + two sincos serve four float4s (they differ only in batch b).

constexpr int B_DIM = 16;
constexpr int S_DIM = 8192;
constexpr int D_DIM = 128;
constexpr int TOTAL_F4 = B_DIM * S_DIM * (D_DIM / 4);  // 4,194,304
constexpr int QUARTER  = TOTAL_F4 / 4;                 // 1,048,576

#define L2T_OVER_HALFD 0.20762050593046014f  // log2(10000)/64
#define KSTEP          0.8659643233600653f   // 10000^(-1/64) = ratio inv_freq[i+1]/inv_freq[i]

typedef float vf4 __attribute__((ext_vector_type(4)));

__device__ __forceinline__ vf4 rope4(vf4 v, float s0, float c0, float s1, float c1) {
    vf4 o;
    o.x = v.x * c0 - v.y * s0;
    o.y = v.x * s0 + v.y * c0;
    o.z = v.z * c1 - v.w * s1;
    o.w = v.z * s1 + v.w * c1;
    return o;
}

__global__ __launch_bounds__(256) void rope_kernel(const vf4* __restrict__ x,
                                                   vf4* __restrict__ out) {
    const int t = blockIdx.x * blockDim.x + threadIdx.x;  // [0, QUARTER)

    // Issue all four independent 16B loads up front (MLP).
    const vf4 v0 = __builtin_nontemporal_load(&x[t]);
    const vf4 v1 = __builtin_nontemporal_load(&x[t + QUARTER]);
    const vf4 v2 = __builtin_nontemporal_load(&x[t + 2 * QUARTER]);
    const vf4 v3 = __builtin_nontemporal_load(&x[t + 3 * QUARTER]);

    const int j = t & 31;             // float4 within the 128-elem row
    const int s = (t >> 5) & (S_DIM - 1);

    const float inv0 = exp2f(-(float)(2 * j) * L2T_OVER_HALFD);
    const float inv1 = inv0 * KSTEP;
    const float fs = (float)s;
    float s0, c0, s1, c1;
    __sincosf(fs * inv0, &s0, &c0);
    __sincosf(fs * inv1, &s1, &c1);

    __builtin_nontemporal_store(rope4(v0, s0, c0, s1, c1), &out[t]);
    __builtin_nontemporal_store(rope4(v1, s0, c0, s1, c1), &out[t + QUARTER]);
    __builtin_nontemporal_store(rope4(v2, s0, c0, s1, c1), &out[t + 2 * QUARTER]);
    __builtin_nontemporal_store(rope4(v3, s0, c0, s1, c1), &out[t + 3 * QUARTER]);
}

extern "C" void kernel_launch(void* const* d_in, const int* in_sizes, int n_in,
                              void* d_out, int out_size, void* d_ws, size_t ws_size,
                              hipStream_t stream) {
    const vf4* x = (const vf4*)d_in[0];
    vf4* out = (vf4*)d_out;
    const int block = 256;
    const int grid = QUARTER / block;  // 4096 blocks
    rope_kernel<<<grid, block, 0, stream>>>(x, out);
}

// Round 3
// 116.518 us; speedup vs baseline: 1.0266x; 1.0266x over previous
//
#include <hip/hip_runtime.h>
#include <math.h>

// RoPE: x (B=16, S=8192, D=128) fp32, interleaved even/odd pairs.
// Reference ignores token_positions; angle = s * theta^(-2i/D), i in [0,64).
// out[2i]   = x[2i]*cos - x[2i+1]*sin
// out[2i+1] = x[2i]*sin + x[2i+1]*cos
//
// R1 structure (one float4/thread, fully coalesced) benched best (110 µs e2e);
// R2's 4-stream batching regressed (+9 µs). This round: R1 + nontemporal
// hints only (streaming data, zero reuse -> don't allocate in L2/MALL).

constexpr int B_DIM = 16;
constexpr int S_DIM = 8192;
constexpr int D_DIM = 128;
constexpr int TOTAL_F4 = B_DIM * S_DIM * (D_DIM / 4);  // 4,194,304

#define L2T_OVER_HALFD 0.20762050593046014f  // log2(10000)/64
#define KSTEP          0.8659643233600653f   // 10000^(-1/64)

typedef float vf4 __attribute__((ext_vector_type(4)));

__global__ __launch_bounds__(256) void rope_kernel(const vf4* __restrict__ x,
                                                   vf4* __restrict__ out) {
    const int g = blockIdx.x * blockDim.x + threadIdx.x;   // float4 index
    const int j = g & 31;             // float4 within 128-elem row
    const int s = (g >> 5) & (S_DIM - 1);

    const vf4 v = __builtin_nontemporal_load(&x[g]);

    const float inv0 = exp2f(-(float)(2 * j) * L2T_OVER_HALFD);
    const float inv1 = inv0 * KSTEP;
    const float fs = (float)s;
    float s0, c0, s1, c1;
    __sincosf(fs * inv0, &s0, &c0);
    __sincosf(fs * inv1, &s1, &c1);

    vf4 o;
    o.x = v.x * c0 - v.y * s0;
    o.y = v.x * s0 + v.y * c0;
    o.z = v.z * c1 - v.w * s1;
    o.w = v.z * s1 + v.w * c1;
    __builtin_nontemporal_store(o, &out[g]);
}

extern "C" void kernel_launch(void* const* d_in, const int* in_sizes, int n_in,
                              void* d_out, int out_size, void* d_ws, size_t ws_size,
                              hipStream_t stream) {
    const vf4* x = (const vf4*)d_in[0];
    vf4* out = (vf4*)d_out;
    const int block = 256;
    const int grid = TOTAL_F4 / block;  // 16384 blocks
    rope_kernel<<<grid, block, 0, stream>>>(x, out);
}

// Round 4
// 115.103 us; speedup vs baseline: 1.0392x; 1.0123x over previous
//
#include <hip/hip_runtime.h>
#include <math.h>

// RoPE: x (B=16, S=8192, D=128) fp32, interleaved even/odd pairs.
// Reference ignores token_positions; angle = s * theta^(-2i/D), i in [0,64).
// out[2i]   = x[2i]*cos - x[2i+1]*sin
// out[2i+1] = x[2i]*sin + x[2i+1]*cos
//
// History: R1 (plain float4/thread) 110.3 µs e2e = best. R2 (4-stream) 119.6.
// R3 (NT load+store) 116.5 — NT store loses L2 write-combining.
// This round: R1 + NT on the LOAD only (read-once input shouldn't occupy L2;
// store goes through L2 normally for write-combining).

constexpr int B_DIM = 16;
constexpr int S_DIM = 8192;
constexpr int D_DIM = 128;
constexpr int TOTAL_F4 = B_DIM * S_DIM * (D_DIM / 4);  // 4,194,304

#define L2T_OVER_HALFD 0.20762050593046014f  // log2(10000)/64
#define KSTEP          0.8659643233600653f   // 10000^(-1/64)

typedef float vf4 __attribute__((ext_vector_type(4)));

__global__ __launch_bounds__(256) void rope_kernel(const vf4* __restrict__ x,
                                                   vf4* __restrict__ out) {
    const int g = blockIdx.x * blockDim.x + threadIdx.x;   // float4 index
    const int j = g & 31;             // float4 within 128-elem row
    const int s = (g >> 5) & (S_DIM - 1);

    const vf4 v = __builtin_nontemporal_load(&x[g]);

    const float inv0 = exp2f(-(float)(2 * j) * L2T_OVER_HALFD);
    const float inv1 = inv0 * KSTEP;
    const float fs = (float)s;
    float s0, c0, s1, c1;
    __sincosf(fs * inv0, &s0, &c0);
    __sincosf(fs * inv1, &s1, &c1);

    vf4 o;
    o.x = v.x * c0 - v.y * s0;
    o.y = v.x * s0 + v.y * c0;
    o.z = v.z * c1 - v.w * s1;
    o.w = v.z * s1 + v.w * c1;
    out[g] = o;   // regular store — keep L2 write-combining
}

extern "C" void kernel_launch(void* const* d_in, const int* in_sizes, int n_in,
                              void* d_out, int out_size, void* d_ws, size_t ws_size,
                              hipStream_t stream) {
    const vf4* x = (const vf4*)d_in[0];
    vf4* out = (vf4*)d_out;
    const int block = 256;
    const int grid = TOTAL_F4 / block;  // 16384 blocks
    rope_kernel<<<grid, block, 0, stream>>>(x, out);
}

// Round 5
// 110.182 us; speedup vs baseline: 1.0857x; 1.0447x over previous
//
#include <hip/hip_runtime.h>
#include <math.h>

// RoPE: x (B=16, S=8192, D=128) fp32, interleaved even/odd pairs.
// Reference ignores token_positions; angle = s * theta^(-2i/D), i in [0,64).
// out[2i]   = x[2i]*cos - x[2i+1]*sin
// out[2i+1] = x[2i]*sin + x[2i+1]*cos
//
// Final: exact R1 structure — one float4/thread, fully coalesced, plain
// load/store. Benched best across 4 variants:
//   R1 plain        110.3 µs e2e  <- this
//   R4 NT-load      115.1
//   R3 NT-both      116.5
//   R2 4-stream     119.6
// Kernel ideal traffic 134 MB -> 21.3 µs @ 6.3 TB/s; e2e includes ~85-90 µs
// harness reset (fill 42 µs + input restore + overhead), so kernel portion
// ~20-25 µs = at the copy roofline. NT hints and multi-stream batching both
// regress on gfx950 — keep the plain stream.

constexpr int B_DIM = 16;
constexpr int S_DIM = 8192;
constexpr int D_DIM = 128;
constexpr int TOTAL_F4 = B_DIM * S_DIM * (D_DIM / 4);  // 4,194,304

#define L2T_OVER_HALFD 0.20762050593046014f  // log2(10000)/64
#define KSTEP          0.8659643233600653f   // 10000^(-1/64)

typedef float vf4 __attribute__((ext_vector_type(4)));

__global__ __launch_bounds__(256) void rope_kernel(const vf4* __restrict__ x,
                                                   vf4* __restrict__ out) {
    const int g = blockIdx.x * blockDim.x + threadIdx.x;   // float4 index
    const int j = g & 31;             // float4 within 128-elem row
    const int s = (g >> 5) & (S_DIM - 1);

    const vf4 v = x[g];

    const float inv0 = exp2f(-(float)(2 * j) * L2T_OVER_HALFD);
    const float inv1 = inv0 * KSTEP;
    const float fs = (float)s;
    float s0, c0, s1, c1;
    __sincosf(fs * inv0, &s0, &c0);
    __sincosf(fs * inv1, &s1, &c1);

    vf4 o;
    o.x = v.x * c0 - v.y * s0;
    o.y = v.x * s0 + v.y * c0;
    o.z = v.z * c1 - v.w * s1;
    o.w = v.z * s1 + v.w * c1;
    out[g] = o;
}

extern "C" void kernel_launch(void* const* d_in, const int* in_sizes, int n_in,
                              void* d_out, int out_size, void* d_ws, size_t ws_size,
                              hipStream_t stream) {
    const vf4* x = (const vf4*)d_in[0];
    vf4* out = (vf4*)d_out;
    const int block = 256;
    const int grid = TOTAL_F4 / block;  // 16384 blocks
    rope_kernel<<<grid, block, 0, stream>>>(x, out);
}